// Round 8
// baseline (27.746 us; speedup 1.0000x reference)
//
#include <hip/hip_runtime.h>
#include <stdint.h>
#include <math.h>

// ---------------------------------------------------------------------------
// SubsetItems, round 8: bit-exact math (absmax 0.0 r1-r7). TWO dispatches:
//   k1 noise    -> packed 64-bit total-order keys; zeroes cnt64[] + done[]
//   k2 rank_out -> per-block j-chunk sort + step-major lower_bound; counts
//                  reduced via packed-u64 device-scope atomicAdd (4 x 16-bit
//                  fields, max 4096 per field -> no carry-out). Last block
//                  per row (done[row] signal) reads counters back with
//                  agent-scope loads and scatters idx+weight.
// r4 lesson: NO __threadfence (buffer_wbl2). Atomics execute at the coherence
// point; vmcnt(0) via __syncthreads before the done++ signal (r5-validated).
// ---------------------------------------------------------------------------

#define RANK_G 64
#define JCHUNK 64
#define IPT    16

struct TF2 { uint32_t a, b; };

__host__ __device__ inline TF2 threefry2x32(uint32_t k0, uint32_t k1,
                                            uint32_t x0, uint32_t x1) {
  const uint32_t ks2 = k0 ^ k1 ^ 0x1BD11BDAu;
#define TF_ROT(v, d) (uint32_t)(((v) << (d)) | ((v) >> (32 - (d))))
#define TF_RND(r) do { x0 += x1; x1 = TF_ROT(x1, r); x1 ^= x0; } while (0)
  x0 += k0; x1 += k1;
  TF_RND(13); TF_RND(15); TF_RND(26); TF_RND(6);
  x0 += k1; x1 += ks2 + 1u;
  TF_RND(17); TF_RND(29); TF_RND(16); TF_RND(24);
  x0 += ks2; x1 += k0 + 2u;
  TF_RND(13); TF_RND(15); TF_RND(26); TF_RND(6);
  x0 += k0; x1 += k1 + 3u;
  TF_RND(17); TF_RND(29); TF_RND(16); TF_RND(24);
  x0 += k1; x1 += ks2 + 4u;
  TF_RND(13); TF_RND(15); TF_RND(26); TF_RND(6);
  x0 += ks2; x1 += k0 + 5u;
#undef TF_RND
#undef TF_ROT
  return {x0, x1};
}

__host__ __device__ __forceinline__ uint32_t random_bits_at(uint32_t ka, uint32_t kb,
                                                            uint32_t idx) {
  TF2 r = threefry2x32(ka, kb, 0u, idx);
  return r.a ^ r.b;
}

// XLA/CHLO ErfInv f32 (bit-exact, verified r1-r7).
__device__ __forceinline__ float erfinv_f32_xla(float x) {
  float xx = __fmul_rn(x, x);
  float v  = -xx;
  float w;
  if (fabsf(v) < 1e-4f) {
    float t = __fmul_rn(__fadd_rn(__fmul_rn(-0.5f, v), 1.0f), v);
    w = -t;
  } else {
    float t = __fadd_rn(v, 1.0f);
    w = -(float)log((double)t);
  }
  float p;
  if (w < 5.0f) {
    float ww = __fadd_rn(w, -2.5f);
    p = 2.81022636e-08f;
    p = __fadd_rn( 3.43273939e-07f, __fmul_rn(p, ww));
    p = __fadd_rn(-3.5233877e-06f,  __fmul_rn(p, ww));
    p = __fadd_rn(-4.39150654e-06f, __fmul_rn(p, ww));
    p = __fadd_rn( 0.00021858087f,  __fmul_rn(p, ww));
    p = __fadd_rn(-0.00125372503f,  __fmul_rn(p, ww));
    p = __fadd_rn(-0.00417768164f,  __fmul_rn(p, ww));
    p = __fadd_rn( 0.246640727f,    __fmul_rn(p, ww));
    p = __fadd_rn( 1.50140941f,     __fmul_rn(p, ww));
  } else {
    float ww = __fadd_rn(__fsqrt_rn(w), -3.0f);
    p = -0.000200214257f;
    p = __fadd_rn( 0.000100950558f, __fmul_rn(p, ww));
    p = __fadd_rn( 0.00134934322f,  __fmul_rn(p, ww));
    p = __fadd_rn(-0.00367342844f,  __fmul_rn(p, ww));
    p = __fadd_rn( 0.00573950773f,  __fmul_rn(p, ww));
    p = __fadd_rn(-0.0076224613f,   __fmul_rn(p, ww));
    p = __fadd_rn( 0.00943887047f,  __fmul_rn(p, ww));
    p = __fadd_rn( 1.00167406f,     __fmul_rn(p, ww));
    p = __fadd_rn( 2.83297682f,     __fmul_rn(p, ww));
  }
  return __fmul_rn(p, x);
}

// Kernel 1: x_noised -> packed 64-bit total-order key; zero cnt64[] + done[].
__global__ __launch_bounds__(256)
void noise_kernel(const float* __restrict__ scores, uint64_t* __restrict__ k64,
                  unsigned long long* __restrict__ cnt64,
                  uint32_t* __restrict__ done,
                  uint32_t k1a, uint32_t k1b, uint32_t k3a, uint32_t k3b,
                  uint32_t rowmask) {
  int e = blockIdx.x * 256 + threadIdx.x;   // 32768
  if (e < 8 * 1024) cnt64[e] = 0ull;        // 8 rows x 1024 packed counters
  if (e < 8) done[e] = 0u;

  int b = e >> 12;
  uint32_t mbits = random_bits_at(k1a, k1b, (uint32_t)e);
  bool mask = ((mbits >> 9) <= 838860u) && ((rowmask >> b) & 1u);

  float s  = scores[e];
  float sf = scores[32767 - e];
  float v  = mask ? fmaxf(s, sf) : s;
  float x  = fminf(fmaxf(v, -1.0f), 1.0f);

  uint32_t nbits = random_bits_at(k3a, k3b, (uint32_t)e);
  float f   = __uint_as_float((nbits >> 9) | 0x3f800000u);
  float f01 = __fadd_rn(f, -1.0f);
  const float lo = __uint_as_float(0xBF7FFFFFu);
  float u = __fadd_rn(__fmul_rn(f01, 2.0f), lo);
  u = fmaxf(lo, u);
  float p    = erfinv_f32_xla(u);
  float nrm  = __fmul_rn(__uint_as_float(0x3FB504F3u), p);
  float nois = __fmul_rn(nrm, 0.0009765625f);
  float xnv  = __fadd_rn(x, nois);

  uint32_t ub = __float_as_uint(xnv);
  uint32_t tk = (ub & 0x80000000u) ? ~ub : (ub | 0x80000000u);
  k64[e] = ((uint64_t)tk << 32) | (uint32_t)(e & 4095);
}

// Kernel 2: rank via sort + step-major lower_bound; packed-u64 atomic
// reduction; last block per row scatters the outputs.
// Counter layout: cnt64[row*1024 + k] field f (16 bits) = rank count of
// item i = k + f*1024. Thread t handles k = q*256+t, q=0..3; its pos[m]
// (i = m*256+t) maps to k-slot q = m&3, field f = m>>2.
__global__ __launch_bounds__(256)
void rank_out_kernel(const uint64_t* __restrict__ k64,
                     unsigned long long* __restrict__ cnt64,
                     uint32_t* __restrict__ done,
                     float* __restrict__ out) {
  __shared__ uint64_t jraw[JCHUNK];
  __shared__ uint64_t jsrt[JCHUNK];
  int row = blockIdx.x >> 6;              // /RANK_G
  int g   = blockIdx.x & (RANK_G - 1);
  const uint64_t* rk = k64 + row * 4096;
  int t = threadIdx.x;

  // i-keys (independent global loads overlap the sort)
  uint64_t ki[IPT];
#pragma unroll
  for (int m = 0; m < IPT; ++m) ki[m] = rk[m * 256 + t];

  if (t < JCHUNK) jraw[t] = rk[g * JCHUNK + t];
  __syncthreads();
  if (t < JCHUNK) {
    uint64_t kt = jraw[t];
    int r = 0;
#pragma unroll 8
    for (int u = 0; u < JCHUNK; ++u) r += (int)(jraw[u] < kt);
    jsrt[r] = kt;                         // keys unique -> exact ranks
  }
  __syncthreads();

  // step-major branchless lower_bound: pos[m] = #{j in chunk : key_j < ki[m]}
  int pos[IPT];
#pragma unroll
  for (int m = 0; m < IPT; ++m) pos[m] = 0;

  const int offs[7] = {31, 15, 7, 3, 1, 0, 0};
  const int incs[7] = {32, 16, 8, 4, 2, 1, 1};
#pragma unroll
  for (int s = 0; s < 7; ++s) {
    uint64_t v[IPT];
#pragma unroll
    for (int m = 0; m < IPT; ++m) v[m] = jsrt[pos[m] + offs[s]];
#pragma unroll
    for (int m = 0; m < IPT; ++m) pos[m] += (v[m] < ki[m]) ? incs[s] : 0;
  }

  // packed-u64 device-scope atomic reduction (4 adds/thread, returning form
  // kept live so completion is vmcnt-tracked before the done++ signal)
  unsigned long long* crow = cnt64 + row * 1024;
#pragma unroll
  for (int q = 0; q < 4; ++q) {
    unsigned long long v = (unsigned long long)(uint32_t)pos[q]
                         | ((unsigned long long)(uint32_t)pos[q + 4]  << 16)
                         | ((unsigned long long)(uint32_t)pos[q + 8]  << 32)
                         | ((unsigned long long)(uint32_t)pos[q + 12] << 48);
    unsigned long long old = atomicAdd(&crow[q * 256 + t], v);
    asm volatile("" :: "v"(old));        // keep returning form (rule #17)
  }

  __syncthreads();   // all 4 waves: vmcnt(0) -> adds complete at TCC
  __shared__ int slast;
  if (t == 0)
    slast = (atomicAdd(&done[row], 1u) == (uint32_t)(RANK_G - 1));
  __syncthreads();
  if (!slast) return;

  // --- last block of this row: read counters (agent-scope), scatter out ---
#pragma unroll
  for (int q = 0; q < 4; ++q) {
    unsigned long long c =
        __hip_atomic_load(&crow[q * 256 + t], __ATOMIC_RELAXED,
                          __HIP_MEMORY_SCOPE_AGENT);
    int k = q * 256 + t;
#pragma unroll
    for (int f = 0; f < 4; ++f) {
      int r = (int)((c >> (16 * f)) & 0xFFFFull);
      if (r >= 2048) {
        int j = r - 2048;
        int i = k + f * 1024;
        out[row * 2048 + j] = (float)i;
        out[16384 + row * 2048 + j] = fminf(__fdiv_rn((float)j, 204.8f), 1.0f);
      }
    }
  }
}

extern "C" void kernel_launch(void* const* d_in, const int* in_sizes, int n_in,
                              void* d_out, int out_size, void* d_ws, size_t ws_size,
                              hipStream_t stream) {
  const float* scores = (const float*)d_in[0];
  float* out = (float*)d_out;

  uint64_t*           k64   = (uint64_t*)d_ws;                        // 256 KB
  unsigned long long* cnt64 = (unsigned long long*)((uint8_t*)d_ws + 32768 * 8); // 64 KB
  uint32_t*           done  = (uint32_t*)((uint8_t*)d_ws + 32768 * 8 + 8192 * 8);

  // split(key(42), 3), partitionable layout (verified r1)
  TF2 K1 = threefry2x32(0u, 42u, 0u, 0u);
  TF2 K2 = threefry2x32(0u, 42u, 0u, 1u);
  TF2 K3 = threefry2x32(0u, 42u, 0u, 2u);

  // batch_mask rows on host: uniform(k2,(8,1)) < 0.75
  uint32_t rowmask = 0;
  for (uint32_t b = 0; b < 8; ++b) {
    uint32_t bits = random_bits_at(K2.a, K2.b, b);
    if ((bits >> 9) < 6291456u) rowmask |= (1u << b);
  }

  noise_kernel<<<128, 256, 0, stream>>>(scores, k64, cnt64, done,
                                        K1.a, K1.b, K3.a, K3.b, rowmask);
  rank_out_kernel<<<8 * RANK_G, 256, 0, stream>>>(k64, cnt64, done, out);
}